// Round 19
// baseline (322.002 us; speedup 1.0000x reference)
//
#include <hip/hip_runtime.h>
#include <math.h>

// SLIC superpixel segmentation — bit-faithful f32 reimplementation of the JAX ref
// (XLA CPU semantics). Numerics decisions, all aimed at exact label match:
//  - dot(feats, centers) replicates Eigen sgemm: sequential k=0..4 FMA chain.
//  - f_sq / c_sq: rounded squares, sequential adds, NO fma (fp contract off).
//  - d = (f_sq + c_sq) - 2*dot, three separately-rounded ops.
//  - argmin == first-min: (d < dmin) || (d == dmin && k < kbest) — order-free.
//  - segment_sum: EXACT ascending-pixel-index sequential adds per cluster.
// Structure: assign fuses tile-local counting sort (per-label segments +
// cnt/start, LDS-staged then coalesced store); update concatenates tile
// segments ascending == ascending pixel order; spatial pruning (R18: phase A
// = 3 nearest grid rows, dmaxB + 1.0f rigorous margin, ballot keep-mask).
// R19 (vs R18's 297us): TPX 512->1024 (4 px/thread, NTILE=49) — halves
// per-block fixed costs and doubles update's gather run lengths (~5 -> ~10,
// better coalescing); loffs via shfl scan (was O(k)-serial LDS loop).
// Order still tiles-asc x (p,w,lane)-lex == ascending n -> bit-identical.

#pragma clang fp contract(off)

#define BATCH 8
#define HH 224
#define WW 224
#define HWPIX (HH * WW)        // 50176
#define KSEG 100
#define TPX 1024               // pixels per tile
#define NTILE 49               // 1024-px tiles per batch (49*1024 == 50176)
#define NITER 10
#define UCH 1024               // update output chunk
#define UPITCH (UCH + 4)       // row stride: 4112B = 257*16, 16B-aligned, staggered banks

__device__ __forceinline__ float get_ratio() {
    double S = sqrt((double)(HH * WW) / (double)KSEG);
    return (float)(10.0 / S);
}

__global__ void k_init(const float* __restrict__ img, float* __restrict__ centers) {
#pragma clang fp contract(off)
    int b = blockIdx.x;
    int k = threadIdx.x;
    if (k >= KSEG) return;
    int i = k / 10, j = k % 10;
    int y = (int)floor(((i + 0.5) * (double)HH) / 10.0);
    int x = (int)floor(((j + 0.5) * (double)WW) / 10.0);
    float ratio = get_ratio();
    int n = y * WW + x;
    const float* p = img + ((size_t)b * HWPIX + n) * 3;
    float* c = centers + (b * KSEG + k) * 5;
    c[0] = (float)y * ratio;
    c[1] = (float)x * ratio;
    c[2] = p[0];
    c[3] = p[1];
    c[4] = p[2];
}

// 4 pixels/thread: n = tile*1024 + p*256 + tid. Ascending n == lex (p, w, lane).
// mode 0: argmin (pruned) + tile-local counting sort -> tileBuf + cnt/start.
// mode 1: final outputs only.
__global__ void k_assign(const float* __restrict__ img, const float* __restrict__ centers,
                         float* __restrict__ tileBuf, int* __restrict__ cntT,
                         int* __restrict__ startT, float* __restrict__ outLab,
                         float* __restrict__ outMean, int mode) {
#pragma clang fp contract(off)
    __shared__ float c8[KSEG * 8];    // [c0..c4, csq, pad, pad]
    __shared__ int whist[16 * KSEG];  // group g = p*4 + w, lex order == pixel order
    __shared__ int tilecnt[KSEG];
    __shared__ int loffs[KSEG];
    __shared__ float sorted[5][TPX];  // LDS staging for sorted tile segments
    __shared__ float wmax[4];
    __shared__ unsigned long long kmask[2];
    __shared__ int sum0s;
    int b = blockIdx.y, tile = blockIdx.x, tid = threadIdx.x;
    int lane = tid & 63, w = tid >> 6;

    for (int i = tid; i < KSEG * 5; i += 256) {
        int k = i / 5, f = i - 5 * k;
        c8[k * 8 + f] = centers[(size_t)b * KSEG * 5 + i];
    }
    if (mode == 0)
        for (int i = tid; i < 16 * KSEG; i += 256) whist[i] = 0;
    __syncthreads();
    if (tid < KSEG) {
        const float* ck = c8 + tid * 8;
        float s = ck[0] * ck[0];             // XLA fused mul+reduce: no fma, seq adds
        s = s + ck[1] * ck[1];
        s = s + ck[2] * ck[2];
        s = s + ck[3] * ck[3];
        s = s + ck[4] * ck[4];
        c8[tid * 8 + 5] = s;
    }
    __syncthreads();

    float ratio = get_ratio();
    int n0 = tile * TPX + tid;
    float yf[4], xf[4], rr[4], gg[4], bb[4], fsq[4], dmin[4];
    int kb[4];
#pragma unroll
    for (int p = 0; p < 4; ++p) {
        int n = n0 + p * 256;
        int y = n / WW, x = n - y * WW;
        yf[p] = (float)y * ratio;
        xf[p] = (float)x * ratio;
        const float* pp = img + ((size_t)b * HWPIX + n) * 3;
        rr[p] = pp[0]; gg[p] = pp[1]; bb[p] = pp[2];
        float s = yf[p] * yf[p];             // no fma, seq adds (XLA reduce)
        s = s + xf[p] * xf[p];
        s = s + rr[p] * rr[p];
        s = s + gg[p] * gg[p];
        s = s + bb[p] * bb[p];
        fsq[p] = s;
        dmin[p] = INFINITY;
        kb[p] = 0;
    }

    // evaluate one cluster exactly (reference op order); order-free first-min rule
#define EVALK(kk)                                                              \
    {                                                                          \
        int k_ = (kk);                                                         \
        float4 v0 = *reinterpret_cast<const float4*>(&c8[k_ * 8]);             \
        float c4v = c8[k_ * 8 + 4];                                            \
        float csqv = c8[k_ * 8 + 5];                                           \
        _Pragma("unroll")                                                      \
        for (int p = 0; p < 4; ++p) {                                          \
            float dot = yf[p] * v0.x;                                          \
            dot = __fmaf_rn(xf[p], v0.y, dot);                                 \
            dot = __fmaf_rn(rr[p], v0.z, dot);                                 \
            dot = __fmaf_rn(gg[p], v0.w, dot);                                 \
            dot = __fmaf_rn(bb[p], c4v, dot);                                  \
            float d = (fsq[p] + csqv) - 2.0f * dot;                            \
            if (d < dmin[p] || (d == dmin[p] && k_ < kb[p])) {                 \
                dmin[p] = d; kb[p] = k_;                                       \
            }                                                                  \
        }                                                                      \
    }

    // ---- phase A: statically nearest cluster grid rows (ascending k)
    int y0t = (tile * TPX) / WW, y1t = (tile * TPX + TPX - 1) / WW;
    int rmid = ((y0t + y1t) / 2) * 10 / HH;          // nearest init grid row
    int rlo = (rmid > 0) ? rmid - 1 : 0;
    int rhi = (rmid < 9) ? rmid + 1 : 9;
    int kA0 = rlo * 10, kA1 = rhi * 10 + 10;         // 20..30 clusters
    for (int k = kA0; k < kA1; ++k) EVALK(k);

    // ---- block-max dmin + rigorous margin
    float tmax = fmaxf(fmaxf(dmin[0], dmin[1]), fmaxf(dmin[2], dmin[3]));
    for (int d = 32; d > 0; d >>= 1) tmax = fmaxf(tmax, __shfl_xor(tmax, d));
    if (lane == 0) wmax[w] = tmax;
    __syncthreads();
    float dmaxB = fmaxf(fmaxf(wmax[0], wmax[1]), fmaxf(wmax[2], wmax[3])) + 1.0f;

    // ---- keep-mask: remaining ks whose y lower bound could still win
    {
        bool keep = false;
        if (tid < KSEG) {
            int k = tid;
            bool instat = (k >= kA0 && k < kA1);
            float cyf = c8[k * 8 + 0];
            float t0 = (float)y0t * ratio - cyf;     // cy below tile range
            float t1 = cyf - (float)y1t * ratio;     // cy above tile range
            float t = fmaxf(fmaxf(t0, t1), 0.0f);
            keep = (!instat) && (t * t <= dmaxB);    // lb <= dmax+margin
        }
        unsigned long long bm = __ballot(keep);
        if (lane == 0 && w < 2) kmask[w] = bm;       // wave0: k0..63, wave1: k64..99
    }
    __syncthreads();

    // ---- phase B: surviving clusters (ascending k within each word)
    {
        unsigned long long m0 = kmask[0], m1 = kmask[1];
        while (m0) { int k = __builtin_ctzll(m0); m0 &= m0 - 1; EVALK(k); }
        while (m1) { int k = 64 + __builtin_ctzll(m1); m1 &= m1 - 1; EVALK(k); }
    }
#undef EVALK

    if (mode == 1) {
#pragma unroll
        for (int p = 0; p < 4; ++p) {
            int n = n0 + p * 256;
            outLab[(size_t)b * HWPIX + n] = (float)kb[p];
            float* om = outMean + ((size_t)b * HWPIX + n) * 3;
            om[0] = c8[kb[p] * 8 + 2];
            om[1] = c8[kb[p] * 8 + 3];
            om[2] = c8[kb[p] * 8 + 4];
        }
        return;
    }

    // ---- tile-local stable counting sort (order: p, wave, lane == ascending n)
    // Leader-ballot rank over DISTINCT labels present in the wave.
    unsigned long long lmask_lt = (lane == 0) ? 0ull : (~0ull >> (64 - lane));
    int rank_w[4], cnt_w[4];
#pragma unroll
    for (int p = 0; p < 4; ++p) {
        unsigned long long todo = __ballot(1);       // all active lanes
        while (todo) {
            int leader = __builtin_ctzll(todo);
            int lval = __shfl(kb[p], leader);
            unsigned long long mset = __ballot(kb[p] == lval);
            if (kb[p] == lval) {
                cnt_w[p] = (int)__popcll(mset);
                rank_w[p] = (int)__popcll(mset & lmask_lt);
            }
            todo &= ~mset;
        }
    }
#pragma unroll
    for (int p = 0; p < 4; ++p)
        if (rank_w[p] == 0) whist[(p * 4 + w) * KSEG + kb[p]] = cnt_w[p];
    __syncthreads();
    if (tid < KSEG) {
        int s = 0;
#pragma unroll
        for (int g = 0; g < 16; ++g) s += whist[g * KSEG + tid];
        tilecnt[tid] = s;
    }
    __syncthreads();
    // exclusive scan of tilecnt[100] via two shfl-scan chunks + carry
    if (tid < 64) {
        int v = tilecnt[tid];
        int incl = v;
        for (int d = 1; d < 64; d <<= 1) {
            int t = __shfl_up(incl, d);
            if (lane >= d) incl += t;
        }
        loffs[tid] = incl - v;
        if (lane == 63) sum0s = incl;
    }
    __syncthreads();
    if (w == 1) {                                    // tid 64..127 -> k 64..99
        int i2 = tid;
        int v = (i2 < KSEG) ? tilecnt[i2] : 0;
        int incl = v;
        for (int d = 1; d < 64; d <<= 1) {
            int t = __shfl_up(incl, d);
            if (lane >= d) incl += t;
        }
        if (i2 < KSEG) loffs[i2] = sum0s + incl - v;
    }
    __syncthreads();
    if (tid < KSEG) {
        cntT[((size_t)b * KSEG + tid) * NTILE + tile] = tilecnt[tid];
        startT[((size_t)b * KSEG + tid) * NTILE + tile] = loffs[tid];
    }

    // sort into LDS (scattered LDS writes, ~2-way aliasing ~= free)
#pragma unroll
    for (int p = 0; p < 4; ++p) {
        int g = p * 4 + w;
        int r = rank_w[p];
        for (int g2 = 0; g2 < g; ++g2) r += whist[g2 * KSEG + kb[p]];
        int pos = loffs[kb[p]] + r;
        sorted[0][pos] = yf[p];
        sorted[1][pos] = xf[p];
        sorted[2][pos] = rr[p];
        sorted[3][pos] = gg[p];
        sorted[4][pos] = bb[p];
    }
    __syncthreads();

    // ONE coalesced flat copy LDS -> tileBuf (5120 contiguous floats)
    float* tb = tileBuf + (size_t)(b * NTILE + tile) * 5 * TPX;
    const float* sflat = &sorted[0][0];
    for (int i = tid; i < 5 * TPX; i += 256) tb[i] = sflat[i];
}

// One block per (batch,cluster). Shfl-scan the 49 descriptors -> dstL (+total
// sentinel). Output-indexed gather: thread j binary-searches dstL (6 steps),
// copies 5 channels coalesced into ubuf. Then 5 lanes run the EXACT ascending
// serial chains via pipelined float4 LDS reads (x,y,z,w index order).
__global__ void k_update(const float* __restrict__ tileBuf, const int* __restrict__ cntT,
                         const int* __restrict__ startT, float* __restrict__ centers) {
#pragma clang fp contract(off)
    __shared__ int srcL[NTILE];
    __shared__ int dstL[NTILE + 1];
    __shared__ float ubuf[5][UPITCH];
    int k = blockIdx.x, b = blockIdx.y, tid = threadIdx.x;
    int lane = tid & 63;

    if (tid < 64) {
        int c = (lane < NTILE) ? cntT[((size_t)b * KSEG + k) * NTILE + lane] : 0;
        int s = (lane < NTILE) ? startT[((size_t)b * KSEG + k) * NTILE + lane] : 0;
        int incl = c;
        for (int d = 1; d < 64; d <<= 1) {   // Hillis-Steele inclusive scan
            int t = __shfl_up(incl, d);
            if (lane >= d) incl += t;
        }
        if (lane < NTILE) { srcL[lane] = s; dstL[lane] = incl - c; }
        if (lane == 63) dstL[NTILE] = incl;  // lanes >= NTILE have c=0 -> incl==total
    }
    __syncthreads();
    int total = dstL[NTILE];

    float acc = 0.f;
    for (int c0 = 0; c0 < total; c0 += UCH) {
        int m = min(UCH, total - c0);
        for (int jj = tid; jj < m; jj += 256) {
            int j = c0 + jj;
            int lo = 0, hi = NTILE;          // dstL[0]=0 <= j < dstL[NTILE]
            while (hi - lo > 1) {            // 6 steps
                int mid = (lo + hi) >> 1;
                if (dstL[mid] <= j) lo = mid; else hi = mid;
            }
            int src = srcL[lo] + (j - dstL[lo]);
            const float* tb = tileBuf + (size_t)(b * NTILE + lo) * 5 * TPX;
#pragma unroll
            for (int ch = 0; ch < 5; ++ch)
                ubuf[ch][jj] = tb[ch * TPX + src];    // coalesced per channel
        }
        __syncthreads();
        if (tid < 5) {
            float a = acc;
            const float4* bp4 = reinterpret_cast<const float4*>(&ubuf[tid][0]);
            int nf4 = m >> 2;
#pragma unroll 4
            for (int i = 0; i < nf4; ++i) {  // loads pipeline; adds ascending
                float4 v = bp4[i];
                a = a + v.x;
                a = a + v.y;
                a = a + v.z;
                a = a + v.w;
            }
            for (int i = nf4 << 2; i < m; ++i) a = a + ubuf[tid][i];
            acc = a;
        }
        __syncthreads();
    }
    if (tid < 5 && total > 0) {              // where(counts>0, sums/counts, old)
        centers[(b * KSEG + k) * 5 + tid] = acc / (float)total;
    }
}

extern "C" void kernel_launch(void* const* d_in, const int* in_sizes, int n_in,
                              void* d_out, int out_size, void* d_ws, size_t ws_size,
                              hipStream_t stream) {
    const float* img = (const float*)d_in[0];
    float* outLab = (float*)d_out;                         // [8,224,224] labels as f32
    float* outMean = outLab + (size_t)BATCH * HWPIX;       // [8,224,224,3]

    char* ws = (char*)d_ws;
    float* centers = (float*)ws;  ws += (size_t)BATCH * KSEG * 5 * sizeof(float);
    float* tileBuf = (float*)ws;  ws += (size_t)BATCH * NTILE * 5 * TPX * sizeof(float);
    int* cntT      = (int*)ws;    ws += (size_t)BATCH * KSEG * NTILE * sizeof(int);
    int* startT    = (int*)ws;    ws += (size_t)BATCH * KSEG * NTILE * sizeof(int);

    k_init<<<dim3(BATCH), 128, 0, stream>>>(img, centers);
    for (int it = 0; it < NITER; ++it) {
        k_assign<<<dim3(NTILE, BATCH), 256, 0, stream>>>(img, centers, tileBuf, cntT,
                                                         startT, outLab, outMean, 0);
        k_update<<<dim3(KSEG, BATCH), 256, 0, stream>>>(tileBuf, cntT, startT, centers);
    }
    k_assign<<<dim3(NTILE, BATCH), 256, 0, stream>>>(img, centers, tileBuf, cntT,
                                                     startT, outLab, outMean, 1);
}

// Round 20
// 297.000 us; speedup vs baseline: 1.0842x; 1.0842x over previous
//
#include <hip/hip_runtime.h>
#include <math.h>

// SLIC superpixel segmentation — bit-faithful f32 reimplementation of the JAX ref
// (XLA CPU semantics). Numerics decisions, all aimed at exact label match:
//  - dot(feats, centers) replicates Eigen sgemm: sequential k=0..4 FMA chain.
//  - f_sq / c_sq: rounded squares, sequential adds, NO fma (fp contract off).
//  - d = (f_sq + c_sq) - 2*dot, three separately-rounded ops.
//  - argmin == first-min: (d < dmin) || (d == dmin && k < kbest) — order-free.
//  - segment_sum: EXACT ascending-pixel-index sequential adds per cluster.
// Structure (R18 base, 297us): assign fuses tile-local counting sort (512-px
// tiles -> per-label LDS-staged segments + cnt/start); update concatenates
// tile segments ascending == ascending pixel order (U=7.3us, R14-measured);
// spatial pruning (phase A = 3 nearest grid rows, dmaxB + 1.0f margin,
// ballot keep-mask) cut argmin 13.4 -> ~7.5us.
// R20: R19's TPX=1024 regressed (322us: 31KB LDS + bigger reg set cut
// occupancy; grid halved) -> reverted to TPX=512. Kept R19's only cheap win:
// loffs exclusive scan via two shfl-chunks + carry (was O(k)-serial LDS loop).
// Same integers -> outputs bit-identical.

#pragma clang fp contract(off)

#define BATCH 8
#define HH 224
#define WW 224
#define HWPIX (HH * WW)        // 50176
#define KSEG 100
#define TPX 512                // pixels per tile
#define NTILE 98               // 512-px tiles per batch (98*512 == 50176)
#define NITER 10
#define UCH 1024               // update output chunk
#define UPITCH (UCH + 4)       // row stride: 4112B = 257*16, 16B-aligned, staggered banks

__device__ __forceinline__ float get_ratio() {
    double S = sqrt((double)(HH * WW) / (double)KSEG);
    return (float)(10.0 / S);
}

__global__ void k_init(const float* __restrict__ img, float* __restrict__ centers) {
#pragma clang fp contract(off)
    int b = blockIdx.x;
    int k = threadIdx.x;
    if (k >= KSEG) return;
    int i = k / 10, j = k % 10;
    int y = (int)floor(((i + 0.5) * (double)HH) / 10.0);
    int x = (int)floor(((j + 0.5) * (double)WW) / 10.0);
    float ratio = get_ratio();
    int n = y * WW + x;
    const float* p = img + ((size_t)b * HWPIX + n) * 3;
    float* c = centers + (b * KSEG + k) * 5;
    c[0] = (float)y * ratio;
    c[1] = (float)x * ratio;
    c[2] = p[0];
    c[3] = p[1];
    c[4] = p[2];
}

// 2 pixels/thread: n = tile*512 + p*256 + tid. Ascending n == lex (p, w, lane).
// mode 0: argmin (pruned) + tile-local counting sort -> tileBuf + cnt/start.
// mode 1: final outputs only.
__global__ void k_assign(const float* __restrict__ img, const float* __restrict__ centers,
                         float* __restrict__ tileBuf, int* __restrict__ cntT,
                         int* __restrict__ startT, float* __restrict__ outLab,
                         float* __restrict__ outMean, int mode) {
#pragma clang fp contract(off)
    __shared__ float c8[KSEG * 8];   // [c0..c4, csq, pad, pad]
    __shared__ int whist[8 * KSEG];  // group g = p*4 + w, lex order == pixel order
    __shared__ int tilecnt[KSEG];
    __shared__ int loffs[KSEG];
    __shared__ float sorted[5][TPX]; // LDS staging for sorted tile segments
    __shared__ float wmax[4];
    __shared__ unsigned long long kmask[2];
    __shared__ int sum0s;
    int b = blockIdx.y, tile = blockIdx.x, tid = threadIdx.x;
    int lane = tid & 63, w = tid >> 6;

    for (int i = tid; i < KSEG * 5; i += 256) {
        int k = i / 5, f = i - 5 * k;
        c8[k * 8 + f] = centers[(size_t)b * KSEG * 5 + i];
    }
    if (mode == 0)
        for (int i = tid; i < 8 * KSEG; i += 256) whist[i] = 0;
    __syncthreads();
    if (tid < KSEG) {
        const float* ck = c8 + tid * 8;
        float s = ck[0] * ck[0];             // XLA fused mul+reduce: no fma, seq adds
        s = s + ck[1] * ck[1];
        s = s + ck[2] * ck[2];
        s = s + ck[3] * ck[3];
        s = s + ck[4] * ck[4];
        c8[tid * 8 + 5] = s;
    }
    __syncthreads();

    float ratio = get_ratio();
    int n0 = tile * TPX + tid;
    float yf[2], xf[2], rr[2], gg[2], bb[2], fsq[2], dmin[2];
    int kb[2];
#pragma unroll
    for (int p = 0; p < 2; ++p) {
        int n = n0 + p * 256;
        int y = n / WW, x = n - y * WW;
        yf[p] = (float)y * ratio;
        xf[p] = (float)x * ratio;
        const float* pp = img + ((size_t)b * HWPIX + n) * 3;
        rr[p] = pp[0]; gg[p] = pp[1]; bb[p] = pp[2];
        float s = yf[p] * yf[p];             // no fma, seq adds (XLA reduce)
        s = s + xf[p] * xf[p];
        s = s + rr[p] * rr[p];
        s = s + gg[p] * gg[p];
        s = s + bb[p] * bb[p];
        fsq[p] = s;
        dmin[p] = INFINITY;
        kb[p] = 0;
    }

    // evaluate one cluster exactly (reference op order); order-free first-min rule
#define EVALK(kk)                                                              \
    {                                                                          \
        int k_ = (kk);                                                         \
        float4 v0 = *reinterpret_cast<const float4*>(&c8[k_ * 8]);             \
        float c4v = c8[k_ * 8 + 4];                                            \
        float csqv = c8[k_ * 8 + 5];                                           \
        _Pragma("unroll")                                                      \
        for (int p = 0; p < 2; ++p) {                                          \
            float dot = yf[p] * v0.x;                                          \
            dot = __fmaf_rn(xf[p], v0.y, dot);                                 \
            dot = __fmaf_rn(rr[p], v0.z, dot);                                 \
            dot = __fmaf_rn(gg[p], v0.w, dot);                                 \
            dot = __fmaf_rn(bb[p], c4v, dot);                                  \
            float d = (fsq[p] + csqv) - 2.0f * dot;                            \
            if (d < dmin[p] || (d == dmin[p] && k_ < kb[p])) {                 \
                dmin[p] = d; kb[p] = k_;                                       \
            }                                                                  \
        }                                                                      \
    }

    // ---- phase A: statically nearest cluster grid rows (ascending k)
    int y0t = (tile * TPX) / WW, y1t = (tile * TPX + TPX - 1) / WW;
    int rmid = ((y0t + y1t) / 2) * 10 / HH;          // nearest init grid row
    int rlo = (rmid > 0) ? rmid - 1 : 0;
    int rhi = (rmid < 9) ? rmid + 1 : 9;
    int kA0 = rlo * 10, kA1 = rhi * 10 + 10;         // 20..30 clusters
    for (int k = kA0; k < kA1; ++k) EVALK(k);

    // ---- block-max dmin + rigorous margin
    float tmax = fmaxf(dmin[0], dmin[1]);
    for (int d = 32; d > 0; d >>= 1) tmax = fmaxf(tmax, __shfl_xor(tmax, d));
    if (lane == 0) wmax[w] = tmax;
    __syncthreads();
    float dmaxB = fmaxf(fmaxf(wmax[0], wmax[1]), fmaxf(wmax[2], wmax[3])) + 1.0f;

    // ---- keep-mask: remaining ks whose y lower bound could still win
    {
        bool keep = false;
        if (tid < KSEG) {
            int k = tid;
            bool instat = (k >= kA0 && k < kA1);
            float cyf = c8[k * 8 + 0];
            float t0 = (float)y0t * ratio - cyf;     // cy below tile range
            float t1 = cyf - (float)y1t * ratio;     // cy above tile range
            float t = fmaxf(fmaxf(t0, t1), 0.0f);
            keep = (!instat) && (t * t <= dmaxB);    // lb <= dmax+margin
        }
        unsigned long long bm = __ballot(keep);
        if (lane == 0 && w < 2) kmask[w] = bm;       // wave0: k0..63, wave1: k64..99
    }
    __syncthreads();

    // ---- phase B: surviving clusters (ascending k within each word)
    {
        unsigned long long m0 = kmask[0], m1 = kmask[1];
        while (m0) { int k = __builtin_ctzll(m0); m0 &= m0 - 1; EVALK(k); }
        while (m1) { int k = 64 + __builtin_ctzll(m1); m1 &= m1 - 1; EVALK(k); }
    }
#undef EVALK

    if (mode == 1) {
#pragma unroll
        for (int p = 0; p < 2; ++p) {
            int n = n0 + p * 256;
            outLab[(size_t)b * HWPIX + n] = (float)kb[p];
            float* om = outMean + ((size_t)b * HWPIX + n) * 3;
            om[0] = c8[kb[p] * 8 + 2];
            om[1] = c8[kb[p] * 8 + 3];
            om[2] = c8[kb[p] * 8 + 4];
        }
        return;
    }

    // ---- tile-local stable counting sort (order: p, wave, lane == ascending n)
    // Leader-ballot rank over DISTINCT labels present in the wave.
    unsigned long long lmask_lt = (lane == 0) ? 0ull : (~0ull >> (64 - lane));
    int rank_w[2], cnt_w[2];
#pragma unroll
    for (int p = 0; p < 2; ++p) {
        unsigned long long todo = __ballot(1);       // all active lanes
        while (todo) {
            int leader = __builtin_ctzll(todo);
            int lval = __shfl(kb[p], leader);
            unsigned long long mset = __ballot(kb[p] == lval);
            if (kb[p] == lval) {
                cnt_w[p] = (int)__popcll(mset);
                rank_w[p] = (int)__popcll(mset & lmask_lt);
            }
            todo &= ~mset;
        }
    }
#pragma unroll
    for (int p = 0; p < 2; ++p)
        if (rank_w[p] == 0) whist[(p * 4 + w) * KSEG + kb[p]] = cnt_w[p];
    __syncthreads();
    if (tid < KSEG) {
        int s = 0;
#pragma unroll
        for (int g = 0; g < 8; ++g) s += whist[g * KSEG + tid];
        tilecnt[tid] = s;
    }
    __syncthreads();
    // exclusive scan of tilecnt[100] via two shfl-scan chunks + carry
    if (tid < 64) {
        int v = tilecnt[tid];
        int incl = v;
        for (int d = 1; d < 64; d <<= 1) {
            int t = __shfl_up(incl, d);
            if (lane >= d) incl += t;
        }
        loffs[tid] = incl - v;
        if (lane == 63) sum0s = incl;
    }
    __syncthreads();
    if (w == 1) {                                    // tid 64..127 -> k 64..99
        int i2 = tid;
        int v = (i2 < KSEG) ? tilecnt[i2] : 0;
        int incl = v;
        for (int d = 1; d < 64; d <<= 1) {
            int t = __shfl_up(incl, d);
            if (lane >= d) incl += t;
        }
        if (i2 < KSEG) loffs[i2] = sum0s + incl - v;
    }
    __syncthreads();
    if (tid < KSEG) {
        cntT[((size_t)b * KSEG + tid) * NTILE + tile] = tilecnt[tid];
        startT[((size_t)b * KSEG + tid) * NTILE + tile] = loffs[tid];
    }

    // sort into LDS (scattered LDS writes, ~2-way aliasing ~= free)
#pragma unroll
    for (int p = 0; p < 2; ++p) {
        int g = p * 4 + w;
        int r = rank_w[p];
        for (int g2 = 0; g2 < g; ++g2) r += whist[g2 * KSEG + kb[p]];
        int pos = loffs[kb[p]] + r;
        sorted[0][pos] = yf[p];
        sorted[1][pos] = xf[p];
        sorted[2][pos] = rr[p];
        sorted[3][pos] = gg[p];
        sorted[4][pos] = bb[p];
    }
    __syncthreads();

    // ONE coalesced flat copy LDS -> tileBuf (2560 contiguous floats)
    float* tb = tileBuf + (size_t)(b * NTILE + tile) * 5 * TPX;
    const float* sflat = &sorted[0][0];
    for (int i = tid; i < 5 * TPX; i += 256) tb[i] = sflat[i];
}

// One block per (batch,cluster). Chunked shfl-scan of the 98 descriptors ->
// dstL (+total sentinel). Output-indexed gather: thread j binary-searches dstL
// (7 steps), copies 5 channels coalesced into ubuf. Then 5 lanes run the EXACT
// ascending serial chains via pipelined float4 LDS reads (x,y,z,w index order).
__global__ void k_update(const float* __restrict__ tileBuf, const int* __restrict__ cntT,
                         const int* __restrict__ startT, float* __restrict__ centers) {
#pragma clang fp contract(off)
    __shared__ int srcL[NTILE];
    __shared__ int dstL[NTILE + 1];
    __shared__ float ubuf[5][UPITCH];
    int k = blockIdx.x, b = blockIdx.y, tid = threadIdx.x;
    int lane = tid & 63;

    if (tid < 64) {
        int carry = 0;
        for (int c0 = 0; c0 < NTILE; c0 += 64) {
            int idx = c0 + lane;
            int c = (idx < NTILE) ? cntT[((size_t)b * KSEG + k) * NTILE + idx] : 0;
            int s = (idx < NTILE) ? startT[((size_t)b * KSEG + k) * NTILE + idx] : 0;
            int incl = c;
            for (int d = 1; d < 64; d <<= 1) {   // Hillis-Steele inclusive scan
                int t = __shfl_up(incl, d);
                if (lane >= d) incl += t;
            }
            if (idx < NTILE) { srcL[idx] = s; dstL[idx] = carry + incl - c; }
            carry += __shfl(incl, 63);
        }
        if (lane == 0) dstL[NTILE] = carry;
    }
    __syncthreads();
    int total = dstL[NTILE];

    float acc = 0.f;
    for (int c0 = 0; c0 < total; c0 += UCH) {
        int m = min(UCH, total - c0);
        for (int jj = tid; jj < m; jj += 256) {
            int j = c0 + jj;
            int lo = 0, hi = NTILE;          // dstL[0]=0 <= j < dstL[NTILE]
            while (hi - lo > 1) {            // 7 steps
                int mid = (lo + hi) >> 1;
                if (dstL[mid] <= j) lo = mid; else hi = mid;
            }
            int src = srcL[lo] + (j - dstL[lo]);
            const float* tb = tileBuf + (size_t)(b * NTILE + lo) * 5 * TPX;
#pragma unroll
            for (int ch = 0; ch < 5; ++ch)
                ubuf[ch][jj] = tb[ch * TPX + src];    // coalesced per channel
        }
        __syncthreads();
        if (tid < 5) {
            float a = acc;
            const float4* bp4 = reinterpret_cast<const float4*>(&ubuf[tid][0]);
            int nf4 = m >> 2;
#pragma unroll 4
            for (int i = 0; i < nf4; ++i) {  // loads pipeline; adds ascending
                float4 v = bp4[i];
                a = a + v.x;
                a = a + v.y;
                a = a + v.z;
                a = a + v.w;
            }
            for (int i = nf4 << 2; i < m; ++i) a = a + ubuf[tid][i];
            acc = a;
        }
        __syncthreads();
    }
    if (tid < 5 && total > 0) {              // where(counts>0, sums/counts, old)
        centers[(b * KSEG + k) * 5 + tid] = acc / (float)total;
    }
}

extern "C" void kernel_launch(void* const* d_in, const int* in_sizes, int n_in,
                              void* d_out, int out_size, void* d_ws, size_t ws_size,
                              hipStream_t stream) {
    const float* img = (const float*)d_in[0];
    float* outLab = (float*)d_out;                         // [8,224,224] labels as f32
    float* outMean = outLab + (size_t)BATCH * HWPIX;       // [8,224,224,3]

    char* ws = (char*)d_ws;
    float* centers = (float*)ws;  ws += (size_t)BATCH * KSEG * 5 * sizeof(float);
    float* tileBuf = (float*)ws;  ws += (size_t)BATCH * NTILE * 5 * TPX * sizeof(float);
    int* cntT      = (int*)ws;    ws += (size_t)BATCH * KSEG * NTILE * sizeof(int);
    int* startT    = (int*)ws;    ws += (size_t)BATCH * KSEG * NTILE * sizeof(int);

    k_init<<<dim3(BATCH), 128, 0, stream>>>(img, centers);
    for (int it = 0; it < NITER; ++it) {
        k_assign<<<dim3(NTILE, BATCH), 256, 0, stream>>>(img, centers, tileBuf, cntT,
                                                         startT, outLab, outMean, 0);
        k_update<<<dim3(KSEG, BATCH), 256, 0, stream>>>(tileBuf, cntT, startT, centers);
    }
    k_assign<<<dim3(NTILE, BATCH), 256, 0, stream>>>(img, centers, tileBuf, cntT,
                                                     startT, outLab, outMean, 1);
}